// Round 1
// baseline (916.453 us; speedup 1.0000x reference)
//
#include <hip/hip_runtime.h>
#include <cstddef>

#define B 8

__device__ constexpr float DM = 0.95122942450071400910f; // exp(-1/20) in f32
__device__ constexpr float DS = 0.81873075307798185867f; // exp(-1/5) in f32

constexpr int N_IN = B * 3 * 32 * 32;     // 24576
constexpr int N_L1 = B * 64 * 32 * 32;    // 524288
constexpr int N_L2 = B * 128 * 32 * 32;   // 1048576
constexpr int N_P1 = B * 128 * 16 * 16;   // 262144
constexpr int N_L3 = B * 256 * 16 * 16;   // 524288
constexpr int N_P2 = B * 256 * 8 * 8;     // 131072
constexpr int N_L4 = B * 512 * 8 * 8;     // 262144
constexpr int N_L5 = B * 256 * 8 * 8;     // 131072
constexpr int N_F1 = B * 1024;            // 8192
constexpr int N_F2 = B * 512;             // 4096
constexpr int N_F3 = B * 10;              // 80

// ---- workspace float layout ----
// zero-initialized region
constexpr size_t O_IN_U = 0;
constexpr size_t O_UM1 = O_IN_U + N_IN;
constexpr size_t O_US1 = O_UM1 + N_L1;
constexpr size_t O_CT1 = O_US1 + N_L1;
constexpr size_t O_UM2 = O_CT1 + N_L1;
constexpr size_t O_US2 = O_UM2 + N_L2;
constexpr size_t O_CT2 = O_US2 + N_L2;
constexpr size_t O_SP2 = O_CT2 + N_L2;
constexpr size_t O_P1E = O_SP2 + N_L2;
constexpr size_t O_UM3 = O_P1E + N_L2;
constexpr size_t O_US3 = O_UM3 + N_L3;
constexpr size_t O_CT3 = O_US3 + N_L3;
constexpr size_t O_SP3 = O_CT3 + N_L3;
constexpr size_t O_P2E = O_SP3 + N_L3;
constexpr size_t O_UM4 = O_P2E + N_L3;
constexpr size_t O_US4 = O_UM4 + N_L4;
constexpr size_t O_CT4 = O_US4 + N_L4;
constexpr size_t O_UM5 = O_CT4 + N_L4;
constexpr size_t O_US5 = O_UM5 + N_L5;
constexpr size_t O_CT5 = O_US5 + N_L5;
constexpr size_t O_UMF1 = O_CT5 + N_L5;
constexpr size_t O_USF1 = O_UMF1 + N_F1;
constexpr size_t O_CTF1 = O_USF1 + N_F1;
constexpr size_t O_UMF2 = O_CTF1 + N_F1;
constexpr size_t O_USF2 = O_UMF2 + N_F2;
constexpr size_t O_CTF2 = O_USF2 + N_F2;
constexpr size_t O_UMF3 = O_CTF2 + N_F2;
constexpr size_t O_USF3 = O_UMF3 + N_F3;
constexpr size_t O_CTF3 = O_USF3 + N_F3;
constexpr size_t O_TE = O_CTF3 + N_F3;
constexpr size_t ZEND = O_TE + N_F3;
// ones-initialized region (sav)
constexpr size_t O_SAV1 = ZEND;
constexpr size_t O_SAV2 = O_SAV1 + N_L1;
constexpr size_t O_SAV3 = O_SAV2 + N_L2;
constexpr size_t O_SAV4 = O_SAV3 + N_L3;
constexpr size_t O_SAV5 = O_SAV4 + N_L4;
constexpr size_t O_SAVF1 = O_SAV5 + N_L5;
constexpr size_t O_SAVF2 = O_SAVF1 + N_F1;
constexpr size_t O_SAVF3 = O_SAVF2 + N_F2;
constexpr size_t OEND = O_SAVF3 + N_F3;
constexpr size_t N_ONES = OEND - ZEND;
// eight-initialized region (latency maps)
constexpr size_t O_P1L = OEND;
constexpr size_t O_P2L = O_P1L + N_L2;
constexpr size_t EEND = O_P2L + N_L3;
constexpr size_t N_EIGHTS = EEND - OEND;
constexpr size_t FLOAT_TOTAL = EEND;
// ---- workspace int layout (after floats) ----
constexpr size_t I_L0 = 0;                 // input spikes list
constexpr size_t I_L1 = I_L0 + N_IN;       // sp1 list
constexpr size_t I_L2P = I_L1 + N_L1;      // pooled sp2 list
constexpr size_t I_L3P = I_L2P + N_P1;     // pooled sp3 list
constexpr size_t I_L4 = I_L3P + N_P2;      // sp4 list
constexpr size_t I_L5 = I_L4 + N_L4;       // sp5 list
constexpr size_t I_LF1 = I_L5 + N_L5;      // spf1 list
constexpr size_t I_LF2 = I_LF1 + N_F1;     // spf2 list
constexpr size_t I_CNT = I_LF2 + N_F2;     // 8 counters
constexpr size_t INT_TOTAL = I_CNT + 8;
constexpr size_t WS_NEED = FLOAT_TOTAL * sizeof(float) + INT_TOTAL * sizeof(int);

__global__ void k_fill(float* p, size_t n, float v) {
  size_t i = (size_t)blockIdx.x * blockDim.x + threadIdx.x;
  size_t st = (size_t)gridDim.x * blockDim.x;
  for (; i < n; i += st) p[i] = v;
}

__global__ void k_zero_counts(int* c) {
  int i = threadIdx.x;
  if (i < 8) c[i] = 0;
}

// input encoding neuron: leaky integrate (DM), thresh 1, reset on spike
__global__ void k_encode(const float* __restrict__ in, float* __restrict__ in_u,
                         int* __restrict__ list, int* __restrict__ cnt,
                         float* __restrict__ sum_slot) {
  int i = blockIdx.x * blockDim.x + threadIdx.x;
  if (i >= N_IN) return;
  float u = DM * in_u[i] + in[i] * 0.2f;
  float sp = (u - 1.0f > 0.0f) ? 1.0f : 0.0f;
  in_u[i] = u * (1.0f - sp);
  if (sp != 0.0f) {
    int p = atomicAdd(cnt, 1);
    list[p] = i;
    atomicAdd(sum_slot, 1.0f);
  }
}

// scatter each spike's weight patch into contrib (same contribution feeds um and us)
template <int CIN, int COUT, int H, int W>
__global__ void k_conv_scatter(const int* __restrict__ list, const int* __restrict__ cnt,
                               const float* __restrict__ w, float* __restrict__ contrib) {
  int total = (*cnt) * COUT;
  int stride = gridDim.x * blockDim.x;
  for (int i = blockIdx.x * blockDim.x + threadIdx.x; i < total; i += stride) {
    int s = i / COUT, oc = i - s * COUT;
    int idx = list[s];
    int b = idx / (CIN * H * W);
    int r = idx - b * (CIN * H * W);
    int c = r / (H * W);
    int p = r - c * (H * W);
    int y = p / W, x = p - y * W;
    const float* wp = w + ((size_t)oc * CIN + c) * 25;
    float* cb = contrib + ((size_t)b * COUT + oc) * (H * W);
#pragma unroll
    for (int ki = 0; ki < 5; ++ki) {
      int oy = y + 2 - ki;
      if ((unsigned)oy < (unsigned)H) {
#pragma unroll
        for (int kj = 0; kj < 5; ++kj) {
          int ox = x + 2 - kj;
          if ((unsigned)ox < (unsigned)W)
            atomicAdd(&cb[oy * W + ox], wp[ki * 5 + kj]);
        }
      }
    }
  }
}

template <int IN, int OUT>
__global__ void k_fc_scatter(const int* __restrict__ list, const int* __restrict__ cnt,
                             const float* __restrict__ w, float* __restrict__ contrib) {
  int total = (*cnt) * OUT;
  int stride = gridDim.x * blockDim.x;
  for (int i = blockIdx.x * blockDim.x + threadIdx.x; i < total; i += stride) {
    int s = i / OUT, o = i - s * OUT;
    int idx = list[s];
    int b = idx / IN, k = idx - b * IN;
    atomicAdd(&contrib[b * OUT + o], w[(size_t)o * IN + k]);
  }
}

// generic NOSO update: um=DM*um+c, us=DS*us+c, u=sav*(um-us), fire, compact spikes
__global__ void k_update_list(float* __restrict__ um, float* __restrict__ us,
                              float* __restrict__ sav, float* __restrict__ ct, int n,
                              int* __restrict__ list, int* __restrict__ cnt,
                              float* __restrict__ sum_slot) {
  int i = blockIdx.x * blockDim.x + threadIdx.x;
  if (i >= n) return;
  float cv = ct[i];
  ct[i] = 0.0f;
  float m = DM * um[i] + cv;
  float s = DS * us[i] + cv;
  um[i] = m;
  us[i] = s;
  float sv = sav[i];
  float u = sv * (m - s);
  if (u - 1.0f > 0.0f) {
    sav[i] = 0.0f;
    int p = atomicAdd(cnt, 1);
    list[p] = i;
    atomicAdd(sum_slot, 1.0f);
  }
}

// update for layers feeding a minpool: also maintain p?e/p?l and write spike mask
__global__ void k_update_pool(float* __restrict__ um, float* __restrict__ us,
                              float* __restrict__ sav, float* __restrict__ ct, int n,
                              float* __restrict__ spmask, float* __restrict__ pe,
                              float* __restrict__ pl, float* __restrict__ sum_slot) {
  int i = blockIdx.x * blockDim.x + threadIdx.x;
  if (i >= n) return;
  float cv = ct[i];
  ct[i] = 0.0f;
  float m = DM * um[i] + cv;
  float s = DS * us[i] + cv;
  um[i] = m;
  us[i] = s;
  float sv = sav[i];
  float u = sv * (m - s);
  float sp = (u - 1.0f > 0.0f) ? 1.0f : 0.0f;
  if (sp != 0.0f) {
    sav[i] = 0.0f;
    atomicAdd(sum_slot, 1.0f);
  }
  float pe_old = pe[i];
  float act = (m != 0.0f) ? 1.0f : 0.0f;
  float pe_new = pe_old + (((pe_old + act) != 0.0f) ? 1.0f : 0.0f);
  pe[i] = pe_new;
  if (sp != 0.0f) pl[i] += (pe_new - 7.0f);  // pl += sp*(pe - NUM_STEPS + 1)
  spmask[i] = sp;
}

// latency min-pool 2x2 (first-min tie-break = jnp.argmin order (0,0),(0,1),(1,0),(1,1)) + compact
__global__ void k_pool_compact(const float* __restrict__ spmask, const float* __restrict__ pl,
                               int* __restrict__ list, int* __restrict__ cnt, int n, int H,
                               int W) {
  int i = blockIdx.x * blockDim.x + threadIdx.x;
  if (i >= n) return;
  int hw = W >> 1, hh = H >> 1;
  int px = i % hw;
  int py = (i / hw) % hh;
  int bc = i / (hw * hh);
  int base = (bc * H + 2 * py) * W + 2 * px;
  float l0 = pl[base], l1 = pl[base + 1], l2 = pl[base + W], l3 = pl[base + W + 1];
  int off = 0;
  float lm = l0;
  if (l1 < lm) { lm = l1; off = 1; }
  if (l2 < lm) { lm = l2; off = W; }
  if (l3 < lm) { lm = l3; off = W + 1; }
  if (spmask[base + off] != 0.0f) {
    int p = atomicAdd(cnt, 1);
    list[p] = i;  // flat index in pooled coords (b, c, py, px)
  }
}

// final FC layer + te/out_t/out_u epilogue
__global__ void k_update_f3(float* __restrict__ um, float* __restrict__ us,
                            float* __restrict__ sav, float* __restrict__ ct,
                            float* __restrict__ te, float* __restrict__ out) {
  int i = threadIdx.x;
  if (i >= N_F3) return;
  float cv = ct[i];
  ct[i] = 0.0f;
  float m = DM * um[i] + cv;
  float s = DS * us[i] + cv;
  um[i] = m;
  us[i] = s;
  float sv = sav[i];
  float u = sv * (m - s);
  float sp = (u - 1.0f > 0.0f) ? 1.0f : 0.0f;
  if (sp != 0.0f) sav[i] = 0.0f;
  float t_old = te[i];
  float act = (u != 0.0f) ? 1.0f : 0.0f;
  float t_new = t_old + (((t_old + act) != 0.0f) ? 1.0f : 0.0f);
  te[i] = t_new;
  out[i] += sp * (t_new - 8.0f);  // out_t (dodt forward)
  out[80 + i] += sp * u;          // out_u
  if (sp != 0.0f) atomicAdd(&out[168], 1.0f);
}

extern "C" void kernel_launch(void* const* d_in, const int* in_sizes, int n_in, void* d_out,
                              int out_size, void* d_ws, size_t ws_size, hipStream_t stream) {
  const float* input = (const float*)d_in[0];
  const float* wc1 = (const float*)d_in[1];
  const float* wc2 = (const float*)d_in[2];
  const float* wc3 = (const float*)d_in[3];
  const float* wc4 = (const float*)d_in[4];
  const float* wc5 = (const float*)d_in[5];
  const float* wf1 = (const float*)d_in[6];
  const float* wf2 = (const float*)d_in[7];
  const float* wf3 = (const float*)d_in[8];
  float* out = (float*)d_out;
  float* ws = (float*)d_ws;
  int* iws = (int*)((char*)d_ws + FLOAT_TOTAL * sizeof(float));
  int* cnt = iws + I_CNT;
  if (ws_size < WS_NEED) return;  // ~64.5 MB needed

  // init: whole ws to 0, then sav=1 and latency maps=NUM_STEPS; out_t=8, out_u=0, sum_sp=0
  hipMemsetAsync(d_ws, 0, WS_NEED, stream);
  k_fill<<<256, 256, 0, stream>>>(ws + ZEND, N_ONES, 1.0f);
  k_fill<<<256, 256, 0, stream>>>(ws + OEND, N_EIGHTS, 8.0f);
  hipMemsetAsync(d_out, 0, 169 * sizeof(float), stream);
  k_fill<<<1, 128, 0, stream>>>(out, 80, 8.0f);

  for (int t = 0; t < 8; ++t) {
    k_zero_counts<<<1, 64, 0, stream>>>(cnt);
    k_encode<<<(N_IN + 255) / 256, 256, 0, stream>>>(input, ws + O_IN_U, iws + I_L0, cnt + 0,
                                                     out + 160);
    k_conv_scatter<3, 64, 32, 32><<<128, 256, 0, stream>>>(iws + I_L0, cnt + 0, wc1, ws + O_CT1);
    k_update_list<<<N_L1 / 256, 256, 0, stream>>>(ws + O_UM1, ws + O_US1, ws + O_SAV1, ws + O_CT1,
                                                  N_L1, iws + I_L1, cnt + 1, out + 161);
    k_conv_scatter<64, 128, 32, 32><<<128, 256, 0, stream>>>(iws + I_L1, cnt + 1, wc2, ws + O_CT2);
    k_update_pool<<<N_L2 / 256, 256, 0, stream>>>(ws + O_UM2, ws + O_US2, ws + O_SAV2, ws + O_CT2,
                                                  N_L2, ws + O_SP2, ws + O_P1E, ws + O_P1L,
                                                  out + 162);
    k_pool_compact<<<N_P1 / 256, 256, 0, stream>>>(ws + O_SP2, ws + O_P1L, iws + I_L2P, cnt + 2,
                                                   N_P1, 32, 32);
    k_conv_scatter<128, 256, 16, 16><<<128, 256, 0, stream>>>(iws + I_L2P, cnt + 2, wc3,
                                                              ws + O_CT3);
    k_update_pool<<<N_L3 / 256, 256, 0, stream>>>(ws + O_UM3, ws + O_US3, ws + O_SAV3, ws + O_CT3,
                                                  N_L3, ws + O_SP3, ws + O_P2E, ws + O_P2L,
                                                  out + 163);
    k_pool_compact<<<N_P2 / 256, 256, 0, stream>>>(ws + O_SP3, ws + O_P2L, iws + I_L3P, cnt + 3,
                                                   N_P2, 16, 16);
    k_conv_scatter<256, 512, 8, 8><<<128, 256, 0, stream>>>(iws + I_L3P, cnt + 3, wc4, ws + O_CT4);
    k_update_list<<<N_L4 / 256, 256, 0, stream>>>(ws + O_UM4, ws + O_US4, ws + O_SAV4, ws + O_CT4,
                                                  N_L4, iws + I_L4, cnt + 4, out + 164);
    k_conv_scatter<512, 256, 8, 8><<<128, 256, 0, stream>>>(iws + I_L4, cnt + 4, wc5, ws + O_CT5);
    k_update_list<<<N_L5 / 256, 256, 0, stream>>>(ws + O_UM5, ws + O_US5, ws + O_SAV5, ws + O_CT5,
                                                  N_L5, iws + I_L5, cnt + 5, out + 165);
    k_fc_scatter<16384, 1024><<<128, 256, 0, stream>>>(iws + I_L5, cnt + 5, wf1, ws + O_CTF1);
    k_update_list<<<N_F1 / 256, 256, 0, stream>>>(ws + O_UMF1, ws + O_USF1, ws + O_SAVF1,
                                                  ws + O_CTF1, N_F1, iws + I_LF1, cnt + 6,
                                                  out + 166);
    k_fc_scatter<1024, 512><<<64, 256, 0, stream>>>(iws + I_LF1, cnt + 6, wf2, ws + O_CTF2);
    k_update_list<<<N_F2 / 256, 256, 0, stream>>>(ws + O_UMF2, ws + O_USF2, ws + O_SAVF2,
                                                  ws + O_CTF2, N_F2, iws + I_LF2, cnt + 7,
                                                  out + 167);
    k_fc_scatter<512, 10><<<16, 256, 0, stream>>>(iws + I_LF2, cnt + 7, wf3, ws + O_CTF3);
    k_update_f3<<<1, 128, 0, stream>>>(ws + O_UMF3, ws + O_USF3, ws + O_SAVF3, ws + O_CTF3,
                                       ws + O_TE, out);
  }
}

// Round 2
// 322.515 us; speedup vs baseline: 2.8416x; 2.8416x over previous
//
#include <hip/hip_runtime.h>
#include <cstddef>

#define B 8

constexpr float DM = 0.95122942450071400910f; // exp(-1/20) in f32
constexpr float DS = 0.81873075307798185867f; // exp(-1/5) in f32

constexpr int N_IN = B * 3 * 32 * 32;     // 24576
constexpr int N_L1 = B * 64 * 32 * 32;    // 524288
constexpr int N_L2 = B * 128 * 32 * 32;   // 1048576
constexpr int N_P1 = B * 128 * 16 * 16;   // 262144
constexpr int N_L3 = B * 256 * 16 * 16;   // 524288
constexpr int N_P2 = B * 256 * 8 * 8;     // 131072
constexpr int N_L4 = B * 512 * 8 * 8;     // 262144
constexpr int N_L5 = B * 256 * 8 * 8;     // 131072
constexpr int N_F1 = B * 1024;            // 8192
constexpr int N_F2 = B * 512;             // 4096
constexpr int N_F3 = B * 10;              // 80

// ---- workspace float layout ----
// zero-initialized region
constexpr size_t O_IN_U = 0;
constexpr size_t O_UM1 = O_IN_U + N_IN;
constexpr size_t O_US1 = O_UM1 + N_L1;
constexpr size_t O_UM2 = O_US1 + N_L1;
constexpr size_t O_US2 = O_UM2 + N_L2;
constexpr size_t O_P1E = O_US2 + N_L2;
constexpr size_t O_UM3 = O_P1E + N_L2;
constexpr size_t O_US3 = O_UM3 + N_L3;
constexpr size_t O_P2E = O_US3 + N_L3;
constexpr size_t O_UM4 = O_P2E + N_L3;
constexpr size_t O_US4 = O_UM4 + N_L4;
constexpr size_t O_UM5 = O_US4 + N_L4;
constexpr size_t O_US5 = O_UM5 + N_L5;
constexpr size_t O_UMF1 = O_US5 + N_L5;
constexpr size_t O_USF1 = O_UMF1 + N_F1;
constexpr size_t O_UMF2 = O_USF1 + N_F1;
constexpr size_t O_USF2 = O_UMF2 + N_F2;
constexpr size_t O_UMF3 = O_USF2 + N_F2;
constexpr size_t O_USF3 = O_UMF3 + N_F3;
constexpr size_t O_TE = O_USF3 + N_F3;
constexpr size_t ZEND = O_TE + N_F3;
// ones-initialized region (sav)
constexpr size_t O_SAV1 = ZEND;
constexpr size_t O_SAV2 = O_SAV1 + N_L1;
constexpr size_t O_SAV3 = O_SAV2 + N_L2;
constexpr size_t O_SAV4 = O_SAV3 + N_L3;
constexpr size_t O_SAV5 = O_SAV4 + N_L4;
constexpr size_t O_SAVF1 = O_SAV5 + N_L5;
constexpr size_t O_SAVF2 = O_SAVF1 + N_F1;
constexpr size_t O_SAVF3 = O_SAVF2 + N_F2;
constexpr size_t OEND = O_SAVF3 + N_F3;
constexpr size_t N_ONES = OEND - ZEND;
// eight-initialized region (latency maps)
constexpr size_t O_P1L = OEND;
constexpr size_t O_P2L = O_P1L + N_L2;
constexpr size_t EEND = O_P2L + N_L3;
constexpr size_t N_EIGHTS = EEND - OEND;
constexpr size_t FLOAT_TOTAL = EEND;
// ---- workspace int layout (after floats) ----
constexpr size_t I_L0 = 0;                 // input spikes list
constexpr size_t I_L1 = I_L0 + N_IN;       // sp1 list
constexpr size_t I_L2P = I_L1 + N_L1;      // pooled sp2 list
constexpr size_t I_L3P = I_L2P + N_P1;     // pooled sp3 list
constexpr size_t I_L4 = I_L3P + N_P2;      // sp4 list
constexpr size_t I_L5 = I_L4 + N_L4;       // sp5 list
constexpr size_t I_LF1 = I_L5 + N_L5;      // spf1 list
constexpr size_t I_LF2 = I_LF1 + N_F1;     // spf2 list
constexpr size_t I_CNT = I_LF2 + N_F2;     // 64 counters (8 steps x 8 layers), pre-zeroed
constexpr size_t INT_TOTAL = I_CNT + 64;
constexpr size_t WS_NEED = FLOAT_TOTAL * sizeof(float) + INT_TOTAL * sizeof(int);

__global__ void k_fill(float* p, size_t n, float v) {
  size_t i = (size_t)blockIdx.x * blockDim.x + threadIdx.x;
  size_t st = (size_t)gridDim.x * blockDim.x;
  for (; i < n; i += st) p[i] = v;
}

// input encoding neuron: leaky integrate (DM), thresh 1, reset on spike
__global__ void k_encode(const float* __restrict__ in, float* __restrict__ in_u,
                         int* __restrict__ list, int* __restrict__ cnt,
                         float* __restrict__ sum_slot) {
  int i = blockIdx.x * blockDim.x + threadIdx.x;
  if (i >= N_IN) return;
  float u = DM * in_u[i] + in[i] * 0.2f;
  bool sp = (u - 1.0f > 0.0f);
  in_u[i] = sp ? 0.0f : u;
  if (sp) {
    int p = atomicAdd(cnt, 1);
    list[p] = i;
  }
  unsigned long long bal = __ballot(sp);
  if ((threadIdx.x & 63) == 0 && bal) atomicAdd(sum_slot, (float)__popcll(bal));
}

// fused conv layer: LDS spike-scatter + NOSO update (+ pe/pl + 2x2 latency min-pool) + compaction
template <int CIN, int COUT, int H, int W, bool POOL>
__launch_bounds__(256)
__global__ void k_conv_layer(const int* __restrict__ list, const int* __restrict__ cnt_in,
                             const float* __restrict__ w,
                             float* __restrict__ um, float* __restrict__ us,
                             float* __restrict__ sav,
                             float* __restrict__ pe, float* __restrict__ pl,
                             int* __restrict__ out_list, int* __restrict__ out_cnt,
                             float* __restrict__ sum_slot) {
  constexpr int HW = H * W;
  __shared__ float acc[HW];
  __shared__ float plbuf[POOL ? HW : 1];
  __shared__ float spbuf[POOL ? HW : 1];
  const int tid = threadIdx.x;
  const int b = blockIdx.x / COUT;
  const int oc = blockIdx.x % COUT;

  for (int p = tid; p < HW; p += 256) acc[p] = 0.0f;
  __syncthreads();

  // scatter this batch's input spikes' weight patches into the LDS plane
  const int S = *cnt_in;
  for (int s = tid; s < S; s += 256) {
    int idx = list[s];
    int bs = idx / (CIN * HW);
    if (bs != b) continue;
    int r = idx - bs * (CIN * HW);
    int c = r / HW;
    int p = r - c * HW;
    int y = p / W, x = p - y * W;
    const float* wp = w + ((size_t)oc * CIN + c) * 25;
    float wr[25];
#pragma unroll
    for (int k = 0; k < 25; ++k) wr[k] = wp[k];
#pragma unroll
    for (int ki = 0; ki < 5; ++ki) {
      int oy = y + 2 - ki;
      if ((unsigned)oy < (unsigned)H) {
#pragma unroll
        for (int kj = 0; kj < 5; ++kj) {
          int ox = x + 2 - kj;
          if ((unsigned)ox < (unsigned)W) atomicAdd(&acc[oy * W + ox], wr[ki * 5 + kj]);
        }
      }
    }
  }
  __syncthreads();

  // NOSO state update for this (b, oc) plane
  const size_t plane = (size_t)(b * COUT + oc) * HW;
  for (int p = tid; p < HW; p += 256) {
    size_t g = plane + p;
    float cv = acc[p];
    float m = DM * um[g] + cv;
    float s2 = DS * us[g] + cv;
    um[g] = m;
    us[g] = s2;
    float sv = sav[g];
    float u = sv * (m - s2);
    bool sp = (u - 1.0f > 0.0f);
    if (sp) sav[g] = 0.0f;
    unsigned long long bal = __ballot(sp);
    if ((tid & 63) == 0 && bal) atomicAdd(sum_slot, (float)__popcll(bal));
    if constexpr (POOL) {
      float pe_old = pe[g];
      float act = (m != 0.0f) ? 1.0f : 0.0f;
      float pe_new = pe_old + (((pe_old + act) != 0.0f) ? 1.0f : 0.0f);
      pe[g] = pe_new;
      float plv = pl[g];
      if (sp) {
        plv += pe_new - 7.0f;  // pl += sp * (pe - NUM_STEPS + 1)
        pl[g] = plv;
      }
      plbuf[p] = plv;
      spbuf[p] = sp ? 1.0f : 0.0f;
    } else {
      if (sp) {
        int pos = atomicAdd(out_cnt, 1);
        out_list[pos] = (int)g;
      }
    }
  }
  if constexpr (POOL) {
    __syncthreads();
    constexpr int HP = H / 2, WP = W / 2;
    for (int q = tid; q < HP * WP; q += 256) {
      int py = q / WP, px = q - py * WP;
      int b2 = (2 * py) * W + 2 * px;
      float l0 = plbuf[b2], l1 = plbuf[b2 + 1], l2 = plbuf[b2 + W], l3 = plbuf[b2 + W + 1];
      int off = 0;
      float lm = l0;
      if (l1 < lm) { lm = l1; off = 1; }
      if (l2 < lm) { lm = l2; off = W; }
      if (l3 < lm) { lm = l3; off = W + 1; }
      if (spbuf[b2 + off] != 0.0f) {
        int pos = atomicAdd(out_cnt, 1);
        out_list[pos] = (int)(((size_t)(b * COUT + oc) * HP + py) * WP + px);
      }
    }
  }
}

// fused FC layer: register gather + NOSO update + compaction (each thread owns OUT/256 outputs)
template <int IN, int OUT>
__launch_bounds__(256)
__global__ void k_fc_layer(const int* __restrict__ list, const int* __restrict__ cnt_in,
                           const float* __restrict__ w,
                           float* __restrict__ um, float* __restrict__ us,
                           float* __restrict__ sav,
                           int* __restrict__ out_list, int* __restrict__ out_cnt,
                           float* __restrict__ sum_slot) {
  constexpr int OPT = OUT / 256;
  const int tid = threadIdx.x;
  const int b = blockIdx.x;
  float acc[OPT];
#pragma unroll
  for (int t = 0; t < OPT; ++t) acc[t] = 0.0f;
  const int S = *cnt_in;
  for (int s = 0; s < S; ++s) {
    int idx = list[s];
    int bs = idx / IN;
    if (bs != b) continue;
    int k = idx - bs * IN;
#pragma unroll
    for (int t = 0; t < OPT; ++t) acc[t] += w[(size_t)(tid + t * 256) * IN + k];
  }
#pragma unroll
  for (int t = 0; t < OPT; ++t) {
    int o = tid + t * 256;
    size_t g = (size_t)b * OUT + o;
    float cv = acc[t];
    float m = DM * um[g] + cv;
    float s2 = DS * us[g] + cv;
    um[g] = m;
    us[g] = s2;
    float u = sav[g] * (m - s2);
    bool sp = (u - 1.0f > 0.0f);
    if (sp) {
      sav[g] = 0.0f;
      int pos = atomicAdd(out_cnt, 1);
      out_list[pos] = (int)g;
      atomicAdd(sum_slot, 1.0f);
    }
  }
}

// final FC layer (512->10) + te/out_t/out_u epilogue
__global__ void k_fc3(const int* __restrict__ list, const int* __restrict__ cnt_in,
                      const float* __restrict__ w, float* __restrict__ um,
                      float* __restrict__ us, float* __restrict__ sav,
                      float* __restrict__ te, float* __restrict__ out) {
  int i = threadIdx.x;
  if (i >= N_F3) return;
  int b = i / 10, o = i - b * 10;
  float cv = 0.0f;
  int S = *cnt_in;
  for (int s = 0; s < S; ++s) {
    int idx = list[s];
    int bs = idx / 512;
    if (bs != b) continue;
    cv += w[o * 512 + (idx - bs * 512)];
  }
  float m = DM * um[i] + cv;
  float s2 = DS * us[i] + cv;
  um[i] = m;
  us[i] = s2;
  float u = sav[i] * (m - s2);
  float sp = (u - 1.0f > 0.0f) ? 1.0f : 0.0f;
  if (sp != 0.0f) sav[i] = 0.0f;
  float t_old = te[i];
  float act = (u != 0.0f) ? 1.0f : 0.0f;
  float t_new = t_old + (((t_old + act) != 0.0f) ? 1.0f : 0.0f);
  te[i] = t_new;
  out[i] += sp * (t_new - 8.0f);  // out_t (dodt forward)
  out[80 + i] += sp * u;          // out_u
  if (sp != 0.0f) atomicAdd(&out[168], 1.0f);
}

extern "C" void kernel_launch(void* const* d_in, const int* in_sizes, int n_in, void* d_out,
                              int out_size, void* d_ws, size_t ws_size, hipStream_t stream) {
  const float* input = (const float*)d_in[0];
  const float* wc1 = (const float*)d_in[1];
  const float* wc2 = (const float*)d_in[2];
  const float* wc3 = (const float*)d_in[3];
  const float* wc4 = (const float*)d_in[4];
  const float* wc5 = (const float*)d_in[5];
  const float* wf1 = (const float*)d_in[6];
  const float* wf2 = (const float*)d_in[7];
  const float* wf3 = (const float*)d_in[8];
  float* out = (float*)d_out;
  float* ws = (float*)d_ws;
  int* iws = (int*)((char*)d_ws + FLOAT_TOTAL * sizeof(float));
  int* cnt = iws + I_CNT;
  if (ws_size < WS_NEED) return;

  // init: zero state (+ all 64 counters), sav=1, latency maps=8; out_t=8, rest of out=0
  hipMemsetAsync(d_ws, 0, WS_NEED, stream);
  k_fill<<<256, 256, 0, stream>>>(ws + ZEND, N_ONES, 1.0f);
  k_fill<<<256, 256, 0, stream>>>(ws + OEND, N_EIGHTS, 8.0f);
  hipMemsetAsync(d_out, 0, 169 * sizeof(float), stream);
  k_fill<<<1, 128, 0, stream>>>(out, 80, 8.0f);

  for (int t = 0; t < 8; ++t) {
    int* c = cnt + t * 8;
    k_encode<<<(N_IN + 255) / 256, 256, 0, stream>>>(input, ws + O_IN_U, iws + I_L0, c + 0,
                                                     out + 160);
    k_conv_layer<3, 64, 32, 32, false><<<B * 64, 256, 0, stream>>>(
        iws + I_L0, c + 0, wc1, ws + O_UM1, ws + O_US1, ws + O_SAV1, nullptr, nullptr,
        iws + I_L1, c + 1, out + 161);
    k_conv_layer<64, 128, 32, 32, true><<<B * 128, 256, 0, stream>>>(
        iws + I_L1, c + 1, wc2, ws + O_UM2, ws + O_US2, ws + O_SAV2, ws + O_P1E, ws + O_P1L,
        iws + I_L2P, c + 2, out + 162);
    k_conv_layer<128, 256, 16, 16, true><<<B * 256, 256, 0, stream>>>(
        iws + I_L2P, c + 2, wc3, ws + O_UM3, ws + O_US3, ws + O_SAV3, ws + O_P2E, ws + O_P2L,
        iws + I_L3P, c + 3, out + 163);
    k_conv_layer<256, 512, 8, 8, false><<<B * 512, 256, 0, stream>>>(
        iws + I_L3P, c + 3, wc4, ws + O_UM4, ws + O_US4, ws + O_SAV4, nullptr, nullptr,
        iws + I_L4, c + 4, out + 164);
    k_conv_layer<512, 256, 8, 8, false><<<B * 256, 256, 0, stream>>>(
        iws + I_L4, c + 4, wc5, ws + O_UM5, ws + O_US5, ws + O_SAV5, nullptr, nullptr,
        iws + I_L5, c + 5, out + 165);
    k_fc_layer<16384, 1024><<<B, 256, 0, stream>>>(iws + I_L5, c + 5, wf1, ws + O_UMF1,
                                                   ws + O_USF1, ws + O_SAVF1, iws + I_LF1, c + 6,
                                                   out + 166);
    k_fc_layer<1024, 512><<<B, 256, 0, stream>>>(iws + I_LF1, c + 6, wf2, ws + O_UMF2,
                                                 ws + O_USF2, ws + O_SAVF2, iws + I_LF2, c + 7,
                                                 out + 167);
    k_fc3<<<1, 128, 0, stream>>>(iws + I_LF2, c + 7, wf3, ws + O_UMF3, ws + O_USF3, ws + O_SAVF3,
                                 ws + O_TE, out);
  }
}